// Round 8
// baseline (403.209 us; speedup 1.0000x reference)
//
#include <hip/hip_runtime.h>
#include <hip/hip_cooperative_groups.h>
#include <hip/hip_bf16.h>
#include <math.h>

namespace cg = cooperative_groups;

// Problem shape (SimpleGCN):
//   node_features [N=100000, 128] f32
//   edge_index    [2, E=1200000] i32   (row 0 = src, row 1 = dst)
//   post_mask     [P=50000] i32
// out[p] = sigmoid( relu( (emb + segsum(emb[src]->dst))[post[p]] @ Wc + bc ) @ Wo + bo )
//
// Round-19 (vs round-18 @ 185.7us):
//  * ONE COOPERATIVE MEGA-KERNEL. Evidence: all 8 dispatches are individually
//    <40us yet total is 185.7 — generous per-kernel estimates sum to ~100us;
//    the remaining ~80us is inter-dispatch serialization (launch/drain gaps,
//    narrow-kernel tails). Five encode rewrites at a constant ~42us show
//    per-kernel levers are exhausted.
//  * Phases copied verbatim from proven R7 kernels; 6 grid.sync()s replace 7
//    dispatch boundaries. Grid sized via occupancy query (co-residency
//    guaranteed). Full R7 8-dispatch fallback if cooperative launch errors.

#define HIDDEN 64
#define NODE_DIM 128
#define SCAN_CHUNK 1024

typedef __attribute__((ext_vector_type(8))) short short8;   // 8 bf16 (4 VGPR)
typedef __attribute__((ext_vector_type(4))) float floatx4;  // mfma C/D frag

union F2B { short8 s; __hip_bfloat162 h[4]; };
union B2U { __hip_bfloat16 b; unsigned short u; };

__device__ inline short8 cvt8(const float4& p, const float4& q) {
    F2B u;
    u.h[0] = __float22bfloat162_rn(make_float2(p.x, p.y));
    u.h[1] = __float22bfloat162_rn(make_float2(p.z, p.w));
    u.h[2] = __float22bfloat162_rn(make_float2(q.x, q.y));
    u.h[3] = __float22bfloat162_rn(make_float2(q.z, q.w));
    return u.s;
}

// hi/lo bf16 split of 8 floats: hi = bf16(x), lo = bf16(x - float(hi)).
__device__ inline void cvt8_split(const float4& p, const float4& q,
                                  short8& hi, short8& lo) {
    const float f[8] = {p.x, p.y, p.z, p.w, q.x, q.y, q.z, q.w};
    F2B uh, ul;
    #pragma unroll
    for (int jj = 0; jj < 4; ++jj) {
        const float2 v = make_float2(f[2 * jj], f[2 * jj + 1]);
        const __hip_bfloat162 h = __float22bfloat162_rn(v);
        const float2 hv = __bfloat1622float2(h);
        ul.h[jj] = __float22bfloat162_rn(make_float2(v.x - hv.x, v.y - hv.y));
        uh.h[jj] = h;
    }
    hi = uh.s; lo = ul.s;
}

// ===========================================================================
// MEGA-KERNEL: all phases in one cooperative dispatch.
// Phase graph: P0 pre+count0 | P1 encode+count | P2 scan | P3 fill |
//              P4 gather | P5 head | P6 out   (grid.sync between phases)
// ===========================================================================
__global__ __launch_bounds__(256) void k_mega(
    const float* __restrict__ A, const int* __restrict__ srcs,
    const int* __restrict__ dsts, const int* __restrict__ post,
    const float* __restrict__ We, const float* __restrict__ be,
    const float* __restrict__ Wc, const float* __restrict__ bc,
    const float* __restrict__ Wo, const float* __restrict__ bo,
    float* __restrict__ out,
    unsigned int* __restrict__ bits, int* __restrict__ nodelist,
    int* __restrict__ listCnt, unsigned int* __restrict__ partials,
    int* __restrict__ count, int* __restrict__ row_start,
    int* __restrict__ rank, int* __restrict__ slots,
    __hip_bfloat16* __restrict__ emb16, float* __restrict__ msg_c,
    float* __restrict__ res,
    int n_nodes, int n_edges, int n_posts, int n_tiles, int nb)
{
    cg::grid_group grid = cg::this_grid();
    __shared__ unsigned short sW16[NODE_DIM * HIDDEN];   // 16 KB
    __shared__ int sS[256];
    __shared__ int sExc;

    const int tid     = threadIdx.x;
    const int gstride = gridDim.x * 256;
    const int gtid0   = blockIdx.x * 256 + tid;

    // ---- P0: pre (bitmask dedup + nodelist append) + zero count[] ----
    for (int i = gtid0; i < n_nodes; i += gstride) count[i] = 0;
    for (int p = gtid0; p < n_posts; p += gstride) {
        const int n = post[p];
        const unsigned int bit = 1u << (n & 31);
        const unsigned int old = atomicOr(&bits[n >> 5], bit);
        if (!(old & bit)) {
            const int i = atomicAdd(listCnt, 1);
            nodelist[i] = n;
        }
    }
    grid.sync();

    // ---- P1: encode (MFMA) + edge count/rank interleaved ----
    {
        // stage We into LDS as bf16 in MFMA-fragment order
        const float4* src = (const float4*)We;
        #pragma unroll
        for (int i = 0; i < 8; ++i) {
            const int fidx = i * 256 + tid;
            const float4 v = src[fidx];
            #pragma unroll
            for (int c = 0; c < 4; ++c) {
                const int linear = fidx * 4 + c;
                const int k   = linear >> 6;
                const int col = linear & 63;
                const int ks   = k >> 5;
                const int kw   = k & 31;
                const int quad = kw >> 3;
                const int jj   = (kw & 7) >> 1;
                const int b    = kw & 1;
                const int nt   = col >> 4;
                const int r    = col & 15;
                const int dsti = ((((ks * 4 + nt) * 4 + quad) * 16 + r) * 8) + jj * 2 + b;
                const float fv = (c == 0) ? v.x : (c == 1) ? v.y : (c == 2) ? v.z : v.w;
                B2U cv; cv.b = __float2bfloat16(fv);
                sW16[dsti] = cv.u;
            }
        }
        __syncthreads();

        const int lane = tid & 63;
        const int r    = lane & 15;
        const int quad = lane >> 4;

        short8 Wb[4][4];
        #pragma unroll
        for (int ks = 0; ks < 4; ++ks)
            #pragma unroll
            for (int nt = 0; nt < 4; ++nt)
                Wb[ks][nt] = *(const short8*)&sW16[(((ks * 4 + nt) * 4 + quad) * 16 + r) * 8];

        float bias[4];
        #pragma unroll
        for (int nt = 0; nt < 4; ++nt) bias[nt] = be[nt * 16 + r];

        const int wid    = gtid0 >> 6;
        const int nwaves = gridDim.x * 4;
        int e = gtid0;

        for (int t = wid; t < n_tiles; t += nwaves) {
            const float* Arow = A + (size_t)t * 16 * NODE_DIM + (size_t)r * NODE_DIM + quad * 8;
            float4 a[4][2];
            #pragma unroll
            for (int ks = 0; ks < 4; ++ks) {
                a[ks][0] = *(const float4*)(Arow + ks * 32);
                a[ks][1] = *(const float4*)(Arow + ks * 32 + 4);
            }
            // interleaved edge chunk
            #pragma unroll
            for (int q = 0; q < 3; ++q) {
                if (e < n_edges) {
                    const int d = dsts[e];
                    if ((bits[d >> 5] >> (d & 31)) & 1u)
                        rank[e] = atomicAdd(&count[d], 1);
                    e += gstride;
                }
            }
            floatx4 acc[4] = {};
            #pragma unroll
            for (int ks = 0; ks < 4; ++ks) {
                const short8 af = cvt8(a[ks][0], a[ks][1]);
                #pragma unroll
                for (int nt = 0; nt < 4; ++nt)
                    acc[nt] = __builtin_amdgcn_mfma_f32_16x16x32_bf16(af, Wb[ks][nt], acc[nt], 0, 0, 0);
            }
            #pragma unroll
            for (int nt = 0; nt < 4; ++nt)
                #pragma unroll
                for (int g = 0; g < 4; ++g) {
                    const int node = t * 16 + quad * 4 + g;
                    const float h = fmaxf(acc[nt][g] + bias[nt], 0.0f);
                    emb16[(size_t)node * HIDDEN + nt * 16 + r] = __float2bfloat16(h);
                }
        }
        // tail nodes (n_nodes % 16) — 0 for this shape
        const int rem = n_nodes - n_tiles * 16;
        if (rem > 0 && (gtid0 >> 6) == 0) {
            for (int n = n_tiles * 16; n < n_nodes; ++n) {
                float accs = be[lane];
                const float* row = A + (size_t)n * NODE_DIM;
                for (int k = 0; k < NODE_DIM; ++k)
                    accs = fmaf(row[k], We[(size_t)k * HIDDEN + lane], accs);
                emb16[(size_t)n * HIDDEN + lane] = __float2bfloat16(fmaxf(accs, 0.0f));
            }
        }
        // drain remaining edges
        for (; e < n_edges; e += gstride) {
            const int d = dsts[e];
            if ((bits[d >> 5] >> (d & 31)) & 1u)
                rank[e] = atomicAdd(&count[d], 1);
        }
    }
    grid.sync();

    // ---- P2: scan (decoupled lookback, wave-parallel window) ----
    if (blockIdx.x < (unsigned)nb) {
        const int b = blockIdx.x;
        const int base = b * SCAN_CHUNK + tid * 4;
        int c0 = (base + 0 < n_nodes) ? count[base + 0] : 0;
        int c1 = (base + 1 < n_nodes) ? count[base + 1] : 0;
        int c2 = (base + 2 < n_nodes) ? count[base + 2] : 0;
        int c3 = (base + 3 < n_nodes) ? count[base + 3] : 0;
        const int t = c0 + c1 + c2 + c3;
        sS[tid] = t;
        __syncthreads();
        #pragma unroll
        for (int off = 1; off < 256; off <<= 1) {
            int v = (tid >= off) ? sS[tid - off] : 0;
            __syncthreads();
            sS[tid] += v;
            __syncthreads();
        }
        const int total = sS[255];

        if (b == 0) {
            if (tid == 0) {
                __hip_atomic_store(&partials[0], (2u << 30) | (unsigned int)total,
                                   __ATOMIC_RELEASE, __HIP_MEMORY_SCOPE_AGENT);
                sExc = 0;
            }
        } else {
            if (tid == 0) {
                __hip_atomic_store(&partials[b], (1u << 30) | (unsigned int)total,
                                   __ATOMIC_RELEASE, __HIP_MEMORY_SCOPE_AGENT);
            }
            if (tid < 64) {
                int exc = 0;
                int winEnd = b;
                while (true) {
                    const int j = winEnd - 64 + tid;
                    const unsigned int v = (j >= 0)
                        ? __hip_atomic_load(&partials[j], __ATOMIC_ACQUIRE,
                                            __HIP_MEMORY_SCOPE_AGENT)
                        : (2u << 30);
                    const unsigned int st = v >> 30;
                    if (__ballot(st == 0u)) {
                        __builtin_amdgcn_s_sleep(1);
                        continue;
                    }
                    const unsigned long long b2 = __ballot(st == 2u);
                    int contrib;
                    bool done;
                    if (b2) {
                        const int hi = 63 - __clzll(b2);
                        contrib = (tid >= hi) ? (int)(v & 0x3FFFFFFFu) : 0;
                        done = true;
                    } else {
                        contrib = (int)(v & 0x3FFFFFFFu);
                        done = false;
                    }
                    #pragma unroll
                    for (int off = 1; off < 64; off <<= 1)
                        contrib += __shfl_xor(contrib, off);
                    exc += contrib;
                    if (done) break;
                    winEnd -= 64;
                }
                if (tid == 0) {
                    __hip_atomic_store(&partials[b],
                                       (2u << 30) | (unsigned int)(exc + total),
                                       __ATOMIC_RELEASE, __HIP_MEMORY_SCOPE_AGENT);
                    sExc = exc;
                }
            }
        }
        __syncthreads();
        int run = sExc + sS[tid] - t;
        if (base + 0 < n_nodes) row_start[base + 0] = run;   run += c0;
        if (base + 1 < n_nodes) row_start[base + 1] = run;   run += c1;
        if (base + 2 < n_nodes) row_start[base + 2] = run;   run += c2;
        if (base + 3 < n_nodes) row_start[base + 3] = run;
    }
    grid.sync();

    // ---- P3: fill (atomic-free via rank) ----
    for (int e = gtid0; e < n_edges; e += gstride) {
        const int d = dsts[e];
        if (!((bits[d >> 5] >> (d & 31)) & 1u)) continue;
        slots[row_start[d] + rank[e]] = srcs[e];
    }
    grid.sync();

    // ---- P4: gather (one compact node per 8-lane group) ----
    {
        const int lane = tid & 63;
        const int j    = lane & 7;
        const int g    = lane >> 3;
        const int wavei = gtid0 >> 6;
        const int ngroups = gridDim.x * 4 * 8;
        const int nc   = listCnt[0];

        for (int i = wavei * 8 + g; i < nc; i += ngroups) {
            const int n    = nodelist[i];
            const int m    = count[n];
            const int base = row_start[n];

            float2 a0 = {0.f, 0.f}, a1 = {0.f, 0.f}, a2 = {0.f, 0.f}, a3 = {0.f, 0.f};
            #define ACC8(v)  do { F2B u; u.s = (v); float2 t2;                      \
                t2 = __bfloat1622float2(u.h[0]); a0.x += t2.x; a0.y += t2.y;        \
                t2 = __bfloat1622float2(u.h[1]); a1.x += t2.x; a1.y += t2.y;        \
                t2 = __bfloat1622float2(u.h[2]); a2.x += t2.x; a2.y += t2.y;        \
                t2 = __bfloat1622float2(u.h[3]); a3.x += t2.x; a3.y += t2.y; } while (0)

            {
                const short8 v = *(const short8*)(emb16 + (size_t)n * HIDDEN + j * 8);
                ACC8(v);
            }
            int c = 0;
            for (; c + 1 < m; c += 2) {
                const int s0 = slots[base + c];
                const int s1 = slots[base + c + 1];
                const short8 v0 = *(const short8*)(emb16 + (size_t)s0 * HIDDEN + j * 8);
                const short8 v1 = *(const short8*)(emb16 + (size_t)s1 * HIDDEN + j * 8);
                ACC8(v0); ACC8(v1);
            }
            if (c < m) {
                const int s0 = slots[base + c];
                const short8 v0 = *(const short8*)(emb16 + (size_t)s0 * HIDDEN + j * 8);
                ACC8(v0);
            }
            #undef ACC8

            float4* dst = (float4*)(msg_c + (size_t)i * HIDDEN + j * 8);
            dst[0] = make_float4(a0.x, a0.y, a1.x, a1.y);
            dst[1] = make_float4(a2.x, a2.y, a3.x, a3.y);
        }
    }
    grid.sync();

    // ---- P5: head (MFMA over compact msg_c rows) ----
    {
        const int lane = tid & 63;
        const int r    = lane & 15;
        const int quad = lane >> 4;

        short8 Wb[2][4];
        #pragma unroll
        for (int ks = 0; ks < 2; ++ks)
            #pragma unroll
            for (int nt = 0; nt < 4; ++nt) {
                F2B u;
                #pragma unroll
                for (int jj = 0; jj < 4; ++jj) {
                    const int k0 = ks * 32 + quad * 8 + 2 * jj;
                    const float lo = Wc[(size_t)k0 * HIDDEN + nt * 16 + r];
                    const float hi = Wc[(size_t)(k0 + 1) * HIDDEN + nt * 16 + r];
                    u.h[jj] = __float22bfloat162_rn(make_float2(lo, hi));
                }
                Wb[ks][nt] = u.s;
            }
        float bias[4], wo[4];
        #pragma unroll
        for (int nt = 0; nt < 4; ++nt) { bias[nt] = bc[nt * 16 + r]; wo[nt] = Wo[nt * 16 + r]; }
        const float bo_s = bo[0];

        const int nc      = listCnt[0];
        const int nt_h    = (nc + 15) / 16;
        const int wid     = gtid0 >> 6;
        const int nwaves  = gridDim.x * 4;

        for (int tile = wid; tile < nt_h; tile += nwaves) {
            const int i0  = tile * 16;
            const int row = i0 + r;
            floatx4 acc[4] = {};
            #pragma unroll
            for (int ks = 0; ks < 2; ++ks) {
                float4 f0 = make_float4(0.f, 0.f, 0.f, 0.f), f1 = f0;
                if (row < nc) {
                    const float* src2 = msg_c + (size_t)row * HIDDEN + ks * 32 + quad * 8;
                    f0 = *(const float4*)src2;
                    f1 = *(const float4*)(src2 + 4);
                }
                short8 ah, al;
                cvt8_split(f0, f1, ah, al);
                #pragma unroll
                for (int nt = 0; nt < 4; ++nt) {
                    acc[nt] = __builtin_amdgcn_mfma_f32_16x16x32_bf16(ah, Wb[ks][nt], acc[nt], 0, 0, 0);
                    acc[nt] = __builtin_amdgcn_mfma_f32_16x16x32_bf16(al, Wb[ks][nt], acc[nt], 0, 0, 0);
                }
            }
            float r4[4];
            #pragma unroll
            for (int gg = 0; gg < 4; ++gg) {
                float part = 0.0f;
                #pragma unroll
                for (int nt = 0; nt < 4; ++nt)
                    part += fmaxf(acc[nt][gg] + bias[nt], 0.0f) * wo[nt];
                part += __shfl_xor(part, 1);
                part += __shfl_xor(part, 2);
                part += __shfl_xor(part, 4);
                part += __shfl_xor(part, 8);
                r4[gg] = part;
            }
            if (r == 0) {
                #pragma unroll
                for (int gg = 0; gg < 4; ++gg) {
                    const int idx = i0 + quad * 4 + gg;
                    if (idx < nc)
                        res[nodelist[idx]] = 1.0f / (1.0f + __expf(-(r4[gg] + bo_s)));
                }
            }
        }
    }
    grid.sync();

    // ---- P6: out ----
    for (int p = gtid0; p < n_posts; p += gstride) out[p] = res[post[p]];
}

// ===========================================================================
// R7 fallback kernels (used only if cooperative launch fails)
// ===========================================================================
__global__ __launch_bounds__(256) void k_pre(
    const int* __restrict__ post, unsigned int* __restrict__ bits,
    int* __restrict__ nodelist, int* __restrict__ listCnt,
    int* __restrict__ count, int n_posts, int n_nodes)
{
    const int gtid = blockIdx.x * 256 + threadIdx.x;
    if (gtid < n_nodes) count[gtid] = 0;
    if (gtid < n_posts) {
        const int n = post[gtid];
        const unsigned int bit = 1u << (n & 31);
        const unsigned int old = atomicOr(&bits[n >> 5], bit);
        if (!(old & bit)) {
            const int i = atomicAdd(listCnt, 1);
            nodelist[i] = n;
        }
    }
}

__global__ __launch_bounds__(256) void k_encode_count(
    const float* __restrict__ A, const float* __restrict__ We,
    const float* __restrict__ be, __hip_bfloat16* __restrict__ emb16,
    const int* __restrict__ dsts, const unsigned int* __restrict__ bits,
    int* __restrict__ count, int* __restrict__ rank,
    int n_nodes, int n_tiles, int n_edges)
{
    __shared__ unsigned short sW16[NODE_DIM * HIDDEN];
    {
        const float4* src = (const float4*)We;
        #pragma unroll
        for (int i = 0; i < 8; ++i) {
            const int fidx = i * 256 + threadIdx.x;
            const float4 v = src[fidx];
            #pragma unroll
            for (int c = 0; c < 4; ++c) {
                const int linear = fidx * 4 + c;
                const int k   = linear >> 6;
                const int col = linear & 63;
                const int ks   = k >> 5;
                const int kw   = k & 31;
                const int quad = kw >> 3;
                const int jj   = (kw & 7) >> 1;
                const int b    = kw & 1;
                const int nt   = col >> 4;
                const int r    = col & 15;
                const int dst = ((((ks * 4 + nt) * 4 + quad) * 16 + r) * 8) + jj * 2 + b;
                const float fv = (c == 0) ? v.x : (c == 1) ? v.y : (c == 2) ? v.z : v.w;
                B2U cv; cv.b = __float2bfloat16(fv);
                sW16[dst] = cv.u;
            }
        }
    }
    __syncthreads();

    const int lane = threadIdx.x & 63;
    const int r    = lane & 15;
    const int quad = lane >> 4;

    short8 Wb[4][4];
    #pragma unroll
    for (int ks = 0; ks < 4; ++ks)
        #pragma unroll
        for (int nt = 0; nt < 4; ++nt)
            Wb[ks][nt] = *(const short8*)&sW16[(((ks * 4 + nt) * 4 + quad) * 16 + r) * 8];

    float bias[4];
    #pragma unroll
    for (int nt = 0; nt < 4; ++nt) bias[nt] = be[nt * 16 + r];

    const int wid    = (blockIdx.x * 256 + threadIdx.x) >> 6;
    const int nwaves = gridDim.x * 4;
    const int estride = gridDim.x * 256;
    int e = blockIdx.x * 256 + threadIdx.x;

    for (int t = wid; t < n_tiles; t += nwaves) {
        const float* Arow = A + (size_t)t * 16 * NODE_DIM + (size_t)r * NODE_DIM + quad * 8;
        float4 a[4][2];
        #pragma unroll
        for (int ks = 0; ks < 4; ++ks) {
            a[ks][0] = *(const float4*)(Arow + ks * 32);
            a[ks][1] = *(const float4*)(Arow + ks * 32 + 4);
        }
        #pragma unroll
        for (int q = 0; q < 3; ++q) {
            if (e < n_edges) {
                const int d = dsts[e];
                if ((bits[d >> 5] >> (d & 31)) & 1u)
                    rank[e] = atomicAdd(&count[d], 1);
                e += estride;
            }
        }
        floatx4 acc[4] = {};
        #pragma unroll
        for (int ks = 0; ks < 4; ++ks) {
            const short8 af = cvt8(a[ks][0], a[ks][1]);
            #pragma unroll
            for (int nt = 0; nt < 4; ++nt)
                acc[nt] = __builtin_amdgcn_mfma_f32_16x16x32_bf16(af, Wb[ks][nt], acc[nt], 0, 0, 0);
        }
        #pragma unroll
        for (int nt = 0; nt < 4; ++nt)
            #pragma unroll
            for (int g = 0; g < 4; ++g) {
                const int node = t * 16 + quad * 4 + g;
                const float h = fmaxf(acc[nt][g] + bias[nt], 0.0f);
                emb16[(size_t)node * HIDDEN + nt * 16 + r] = __float2bfloat16(h);
            }
    }
    const int rem = n_nodes - n_tiles * 16;
    if (rem > 0 && wid == 0) {
        for (int n = n_tiles * 16; n < n_nodes; ++n) {
            float acc = be[lane];
            const float* row = A + (size_t)n * NODE_DIM;
            for (int k = 0; k < NODE_DIM; ++k)
                acc = fmaf(row[k], We[(size_t)k * HIDDEN + lane], acc);
            emb16[(size_t)n * HIDDEN + lane] = __float2bfloat16(fmaxf(acc, 0.0f));
        }
    }
    for (; e < n_edges; e += estride) {
        const int d = dsts[e];
        if ((bits[d >> 5] >> (d & 31)) & 1u)
            rank[e] = atomicAdd(&count[d], 1);
    }
}

__global__ __launch_bounds__(256) void k_scan_lb(
    const int* __restrict__ count, int* __restrict__ row_start,
    unsigned int* __restrict__ partials, int n)
{
    __shared__ int s[256];
    __shared__ int sExc;
    const int b = blockIdx.x, tid = threadIdx.x;
    const int base = b * SCAN_CHUNK + tid * 4;
    int c0 = (base + 0 < n) ? count[base + 0] : 0;
    int c1 = (base + 1 < n) ? count[base + 1] : 0;
    int c2 = (base + 2 < n) ? count[base + 2] : 0;
    int c3 = (base + 3 < n) ? count[base + 3] : 0;
    const int t = c0 + c1 + c2 + c3;
    s[tid] = t;
    __syncthreads();
    #pragma unroll
    for (int off = 1; off < 256; off <<= 1) {
        int v = (tid >= off) ? s[tid - off] : 0;
        __syncthreads();
        s[tid] += v;
        __syncthreads();
    }
    const int total = s[255];

    if (b == 0) {
        if (tid == 0) {
            __hip_atomic_store(&partials[0], (2u << 30) | (unsigned int)total,
                               __ATOMIC_RELEASE, __HIP_MEMORY_SCOPE_AGENT);
            sExc = 0;
        }
    } else {
        if (tid == 0) {
            __hip_atomic_store(&partials[b], (1u << 30) | (unsigned int)total,
                               __ATOMIC_RELEASE, __HIP_MEMORY_SCOPE_AGENT);
        }
        if (tid < 64) {
            int exc = 0;
            int winEnd = b;
            while (true) {
                const int j = winEnd - 64 + tid;
                const unsigned int v = (j >= 0)
                    ? __hip_atomic_load(&partials[j], __ATOMIC_ACQUIRE,
                                        __HIP_MEMORY_SCOPE_AGENT)
                    : (2u << 30);
                const unsigned int st = v >> 30;
                if (__ballot(st == 0u)) {
                    __builtin_amdgcn_s_sleep(1);
                    continue;
                }
                const unsigned long long b2 = __ballot(st == 2u);
                int contrib;
                bool done;
                if (b2) {
                    const int hi = 63 - __clzll(b2);
                    contrib = (tid >= hi) ? (int)(v & 0x3FFFFFFFu) : 0;
                    done = true;
                } else {
                    contrib = (int)(v & 0x3FFFFFFFu);
                    done = false;
                }
                #pragma unroll
                for (int off = 1; off < 64; off <<= 1)
                    contrib += __shfl_xor(contrib, off);
                exc += contrib;
                if (done) break;
                winEnd -= 64;
            }
            if (tid == 0) {
                __hip_atomic_store(&partials[b],
                                   (2u << 30) | (unsigned int)(exc + total),
                                   __ATOMIC_RELEASE, __HIP_MEMORY_SCOPE_AGENT);
                sExc = exc;
            }
        }
    }
    __syncthreads();
    int run = sExc + s[tid] - t;
    if (base + 0 < n) row_start[base + 0] = run;           run += c0;
    if (base + 1 < n) row_start[base + 1] = run;           run += c1;
    if (base + 2 < n) row_start[base + 2] = run;           run += c2;
    if (base + 3 < n) row_start[base + 3] = run;
}

__global__ __launch_bounds__(256) void k_fill(
    const int* __restrict__ srcs, const int* __restrict__ dsts,
    const unsigned int* __restrict__ bits, const int* __restrict__ row_start,
    const int* __restrict__ rank, int* __restrict__ slots, int n_edges)
{
    const int stride = gridDim.x * 256;
    for (int e = blockIdx.x * 256 + threadIdx.x; e < n_edges; e += stride) {
        const int d = dsts[e];
        if (!((bits[d >> 5] >> (d & 31)) & 1u)) continue;
        slots[row_start[d] + rank[e]] = srcs[e];
    }
}

__global__ __launch_bounds__(256) void k_gather(
    const int* __restrict__ nodelist, const int* __restrict__ listCnt,
    const int* __restrict__ row_start, const int* __restrict__ count,
    const int* __restrict__ slots, const __hip_bfloat16* __restrict__ emb16,
    float* __restrict__ msg_c)
{
    const int lane = threadIdx.x & 63;
    const int j    = lane & 7;
    const int g    = lane >> 3;
    const int wavei = (blockIdx.x * 256 + threadIdx.x) >> 6;
    const int ngroups = gridDim.x * 4 * 8;
    const int nc   = listCnt[0];

    for (int i = wavei * 8 + g; i < nc; i += ngroups) {
        const int n    = nodelist[i];
        const int m    = count[n];
        const int base = row_start[n];

        float2 a0 = {0.f, 0.f}, a1 = {0.f, 0.f}, a2 = {0.f, 0.f}, a3 = {0.f, 0.f};
        #define ACC8(v)  do { F2B u; u.s = (v); float2 t;                       \
            t = __bfloat1622float2(u.h[0]); a0.x += t.x; a0.y += t.y;           \
            t = __bfloat1622float2(u.h[1]); a1.x += t.x; a1.y += t.y;           \
            t = __bfloat1622float2(u.h[2]); a2.x += t.x; a2.y += t.y;           \
            t = __bfloat1622float2(u.h[3]); a3.x += t.x; a3.y += t.y; } while (0)

        {
            const short8 v = *(const short8*)(emb16 + (size_t)n * HIDDEN + j * 8);
            ACC8(v);
        }
        int c = 0;
        for (; c + 1 < m; c += 2) {
            const int s0 = slots[base + c];
            const int s1 = slots[base + c + 1];
            const short8 v0 = *(const short8*)(emb16 + (size_t)s0 * HIDDEN + j * 8);
            const short8 v1 = *(const short8*)(emb16 + (size_t)s1 * HIDDEN + j * 8);
            ACC8(v0); ACC8(v1);
        }
        if (c < m) {
            const int s0 = slots[base + c];
            const short8 v0 = *(const short8*)(emb16 + (size_t)s0 * HIDDEN + j * 8);
            ACC8(v0);
        }
        #undef ACC8

        float4* dst = (float4*)(msg_c + (size_t)i * HIDDEN + j * 8);
        dst[0] = make_float4(a0.x, a0.y, a1.x, a1.y);
        dst[1] = make_float4(a2.x, a2.y, a3.x, a3.y);
    }
}

__global__ __launch_bounds__(256) void k_head_mfma(
    const int* __restrict__ listCnt, const int* __restrict__ nodelist,
    const float* __restrict__ msg_c,
    const float* __restrict__ Wc, const float* __restrict__ bc,
    const float* __restrict__ Wo, const float* __restrict__ bo,
    float* __restrict__ res)
{
    const int lane = threadIdx.x & 63;
    const int r    = lane & 15;
    const int quad = lane >> 4;

    short8 Wb[2][4];
    #pragma unroll
    for (int ks = 0; ks < 2; ++ks)
        #pragma unroll
        for (int nt = 0; nt < 4; ++nt) {
            F2B u;
            #pragma unroll
            for (int jj = 0; jj < 4; ++jj) {
                const int k0 = ks * 32 + quad * 8 + 2 * jj;
                const float lo = Wc[(size_t)k0 * HIDDEN + nt * 16 + r];
                const float hi = Wc[(size_t)(k0 + 1) * HIDDEN + nt * 16 + r];
                u.h[jj] = __float22bfloat162_rn(make_float2(lo, hi));
            }
            Wb[ks][nt] = u.s;
        }
    float bias[4], wo[4];
    #pragma unroll
    for (int nt = 0; nt < 4; ++nt) { bias[nt] = bc[nt * 16 + r]; wo[nt] = Wo[nt * 16 + r]; }
    const float bo_s = bo[0];

    const int nc      = listCnt[0];
    const int n_tiles = (nc + 15) / 16;
    const int wid     = (blockIdx.x * 256 + threadIdx.x) >> 6;
    const int nwaves  = gridDim.x * 4;

    for (int tile = wid; tile < n_tiles; tile += nwaves) {
        const int i0  = tile * 16;
        const int row = i0 + r;
        floatx4 acc[4] = {};
        #pragma unroll
        for (int ks = 0; ks < 2; ++ks) {
            float4 f0 = make_float4(0.f, 0.f, 0.f, 0.f), f1 = f0;
            if (row < nc) {
                const float* src = msg_c + (size_t)row * HIDDEN + ks * 32 + quad * 8;
                f0 = *(const float4*)src;
                f1 = *(const float4*)(src + 4);
            }
            short8 ah, al;
            cvt8_split(f0, f1, ah, al);
            #pragma unroll
            for (int nt = 0; nt < 4; ++nt) {
                acc[nt] = __builtin_amdgcn_mfma_f32_16x16x32_bf16(ah, Wb[ks][nt], acc[nt], 0, 0, 0);
                acc[nt] = __builtin_amdgcn_mfma_f32_16x16x32_bf16(al, Wb[ks][nt], acc[nt], 0, 0, 0);
            }
        }
        float r4[4];
        #pragma unroll
        for (int gg = 0; gg < 4; ++gg) {
            float part = 0.0f;
            #pragma unroll
            for (int nt = 0; nt < 4; ++nt)
                part += fmaxf(acc[nt][gg] + bias[nt], 0.0f) * wo[nt];
            part += __shfl_xor(part, 1);
            part += __shfl_xor(part, 2);
            part += __shfl_xor(part, 4);
            part += __shfl_xor(part, 8);
            r4[gg] = part;
        }
        if (r == 0) {
            #pragma unroll
            for (int gg = 0; gg < 4; ++gg) {
                const int idx = i0 + quad * 4 + gg;
                if (idx < nc)
                    res[nodelist[idx]] = 1.0f / (1.0f + __expf(-(r4[gg] + bo_s)));
            }
        }
    }
}

__global__ __launch_bounds__(256) void k_out(
    const int* __restrict__ post, const float* __restrict__ res,
    float* __restrict__ out, int n_posts)
{
    const int p = blockIdx.x * 256 + threadIdx.x;
    if (p < n_posts) out[p] = res[post[p]];
}

extern "C" void kernel_launch(void* const* d_in, const int* in_sizes, int n_in,
                              void* d_out, int out_size, void* d_ws, size_t ws_size,
                              hipStream_t stream) {
    const float* A    = (const float*)d_in[0];
    const int*   ei   = (const int*)  d_in[1];
    const int*   post = (const int*)  d_in[2];
    const float* We   = (const float*)d_in[3];
    const float* be   = (const float*)d_in[4];
    const float* Wc   = (const float*)d_in[5];
    const float* bc   = (const float*)d_in[6];
    const float* Wo   = (const float*)d_in[7];
    const float* bo   = (const float*)d_in[8];
    float* out = (float*)d_out;

    int n_nodes = in_sizes[0] / NODE_DIM;   // 100000
    int n_edges = in_sizes[1] / 2;          // 1200000
    int n_posts = in_sizes[2];              // 50000

    // ---- workspace layout (~38 MB; every region written before read) ----
    char* p = (char*)d_ws;
    __hip_bfloat16* emb16 = (__hip_bfloat16*)p;  p += (size_t)n_nodes * HIDDEN * 2;  // 12.8 MB
    float* msg_c    = (float*)p;              p += (size_t)n_posts * HIDDEN * 4;     // 12.8 MB
    int*   slots    = (int*)p;                p += (size_t)n_edges * 4;              // 4.8 MB
    int*   rank     = (int*)p;                p += (size_t)n_edges * 4;              // 4.8 MB
    // small ctrl region zeroed by memset: bits | listCnt | partials
    char* zbase = p;
    unsigned int* bits = (unsigned int*)p;    p += ((size_t)(n_nodes + 31) / 32 + 32) * 4;
    int*   listCnt  = (int*)p;                p += 256;
    unsigned int* partials = (unsigned int*)p; p += 1024;
    const size_t zbytes = (size_t)(p - zbase);                                       // ~14 KB
    int*   count    = (int*)p;                p += (size_t)n_nodes * 4;
    int*   row_start= (int*)p;                p += (size_t)n_nodes * 4;
    int*   nodelist = (int*)p;                p += (size_t)n_nodes * 4;
    float* res      = (float*)p;              p += (size_t)n_nodes * 4;

    const int* srcs = ei;
    const int* dsts = ei + n_edges;
    int nb = (n_nodes + SCAN_CHUNK - 1) / SCAN_CHUNK;   // 98
    int n_tiles = n_nodes / 16;

    // grid sizing for cooperative launch (cached; pure queries, capture-safe)
    static int s_grid = 0;
    if (s_grid == 0) {
        hipDeviceProp_t prop;
        if (hipGetDeviceProperties(&prop, 0) != hipSuccess) prop.multiProcessorCount = 256;
        int maxB = 0;
        if (hipOccupancyMaxActiveBlocksPerMultiprocessor(&maxB, k_mega, 256, 0) != hipSuccess || maxB < 1)
            maxB = 1;
        long g = (long)maxB * prop.multiProcessorCount;
        if (g > 2048) g = 2048;
        if (g < 256)  g = 256;   // >= nb (98) required by the scan phase
        s_grid = (int)g;
    }

    (void)hipMemsetAsync(zbase, 0, zbytes, stream);

    void* args[] = {
        (void*)&A, (void*)&srcs, (void*)&dsts, (void*)&post,
        (void*)&We, (void*)&be, (void*)&Wc, (void*)&bc, (void*)&Wo, (void*)&bo,
        (void*)&out,
        (void*)&bits, (void*)&nodelist, (void*)&listCnt, (void*)&partials,
        (void*)&count, (void*)&row_start, (void*)&rank, (void*)&slots,
        (void*)&emb16, (void*)&msg_c, (void*)&res,
        (void*)&n_nodes, (void*)&n_edges, (void*)&n_posts, (void*)&n_tiles, (void*)&nb
    };
    hipError_t err = hipLaunchCooperativeKernel((const void*)k_mega, dim3(s_grid), dim3(256),
                                                args, 0, stream);
    if (err != hipSuccess) {
        // fallback: proven R7 8-dispatch pipeline
        k_pre<<<(n_nodes + 255) / 256, 256, 0, stream>>>(post, bits, nodelist, listCnt, count, n_posts, n_nodes);
        k_encode_count<<<1536, 256, 0, stream>>>(A, We, be, emb16, dsts, bits, count, rank, n_nodes, n_tiles, n_edges);
        k_scan_lb<<<nb, 256, 0, stream>>>(count, row_start, partials, n_nodes);
        k_fill<<<2048, 256, 0, stream>>>(srcs, dsts, bits, row_start, rank, slots, n_edges);
        k_gather<<<2048, 256, 0, stream>>>(nodelist, listCnt, row_start, count, slots, emb16, msg_c);
        k_head_mfma<<<1024, 256, 0, stream>>>(listCnt, nodelist, msg_c, Wc, bc, Wo, bo, res);
        k_out<<<(n_posts + 255) / 256, 256, 0, stream>>>(post, res, out, n_posts);
    }
}

// Round 9
// 181.895 us; speedup vs baseline: 2.2167x; 2.2167x over previous
//
#include <hip/hip_runtime.h>
#include <hip/hip_bf16.h>
#include <math.h>

// Problem shape (SimpleGCN):
//   node_features [N=100000, 128] f32
//   edge_index    [2, E=1200000] i32   (row 0 = src, row 1 = dst)
//   post_mask     [P=50000] i32
// out[p] = sigmoid( relu( (emb + segsum(emb[src]->dst))[post[p]] @ Wc + bc ) @ Wo + bo )
//
// Round-20 (vs R7 @ 185.7us; R8 mega-kernel REVERTED):
//  * R8 lesson: ROCm grid.sync at 2048 blocks ~ 80us each (6 syncs = 480us,
//    k_mega 613us, HBM 2.8%). Dispatch boundaries (~12us) are cheaper. Revert.
//  * NEW: k_gather_head — gather+head fused with NO sync: the head tile's 16
//    msg rows are gathered by the same wave that runs the head MFMA. Lane
//    (r,quad) accumulates node nodelist[i0+r] channels [quad*8,+8) and
//    [32+quad*8,+8) in f32 regs == exactly the A-fragment f0/f1 cvt8_split
//    consumes. Deletes one dispatch, the 12.8MB msg_c write and 12.8MB read.
//  * everything else byte-identical to R7.

#define HIDDEN 64
#define NODE_DIM 128
#define SCAN_CHUNK 1024

typedef __attribute__((ext_vector_type(8))) short short8;   // 8 bf16 (4 VGPR)
typedef __attribute__((ext_vector_type(4))) float floatx4;  // mfma C/D frag

union F2B { short8 s; __hip_bfloat162 h[4]; };
union B2U { __hip_bfloat16 b; unsigned short u; };

__device__ inline short8 cvt8(const float4& p, const float4& q) {
    F2B u;
    u.h[0] = __float22bfloat162_rn(make_float2(p.x, p.y));
    u.h[1] = __float22bfloat162_rn(make_float2(p.z, p.w));
    u.h[2] = __float22bfloat162_rn(make_float2(q.x, q.y));
    u.h[3] = __float22bfloat162_rn(make_float2(q.z, q.w));
    return u.s;
}

// hi/lo bf16 split of 8 floats: hi = bf16(x), lo = bf16(x - float(hi)).
__device__ inline void cvt8_split(const float4& p, const float4& q,
                                  short8& hi, short8& lo) {
    const float f[8] = {p.x, p.y, p.z, p.w, q.x, q.y, q.z, q.w};
    F2B uh, ul;
    #pragma unroll
    for (int jj = 0; jj < 4; ++jj) {
        const float2 v = make_float2(f[2 * jj], f[2 * jj + 1]);
        const __hip_bfloat162 h = __float22bfloat162_rn(v);
        const float2 hv = __bfloat1622float2(h);
        ul.h[jj] = __float22bfloat162_rn(make_float2(v.x - hv.x, v.y - hv.y));
        uh.h[jj] = h;
    }
    hi = uh.s; lo = ul.s;
}

// ---------------------------------------------------------------------------
// k_pre: bitmask dedup (atomicOr return) + compact nodelist append + zero
// count[]. bits/listCnt pre-zeroed by the 14 KB memset.
// ---------------------------------------------------------------------------
__global__ __launch_bounds__(256) void k_pre(
    const int* __restrict__ post, unsigned int* __restrict__ bits,
    int* __restrict__ nodelist, int* __restrict__ listCnt,
    int* __restrict__ count, int n_posts, int n_nodes)
{
    const int gtid = blockIdx.x * 256 + threadIdx.x;
    if (gtid < n_nodes) count[gtid] = 0;
    if (gtid < n_posts) {
        const int n = post[gtid];
        const unsigned int bit = 1u << (n & 31);
        const unsigned int old = atomicOr(&bits[n >> 5], bit);
        if (!(old & bit)) {
            const int i = atomicAdd(listCnt, 1);
            nodelist[i] = n;
        }
    }
}

// ---------------------------------------------------------------------------
// Stage 1 (MFMA): emb16 = bf16(relu(A @ We + be)), interleaved with CSR
// step 1 (in-degree count + rank persist). We staged in LDS as bf16 in
// MFMA-fragment order; Wb build = 16 conflict-free ds_read_b128.
// ---------------------------------------------------------------------------
__global__ __launch_bounds__(256) void k_encode_count(
    const float* __restrict__ A, const float* __restrict__ We,
    const float* __restrict__ be, __hip_bfloat16* __restrict__ emb16,
    const int* __restrict__ dsts, const unsigned int* __restrict__ bits,
    int* __restrict__ count, int* __restrict__ rank,
    int n_nodes, int n_tiles, int n_edges)
{
    __shared__ unsigned short sW16[NODE_DIM * HIDDEN];   // 16 KB, fragment order

    {
        const float4* src = (const float4*)We;
        #pragma unroll
        for (int i = 0; i < 8; ++i) {                 // 8*256*4 = 8192 floats
            const int fidx = i * 256 + threadIdx.x;   // float4 index
            const float4 v = src[fidx];
            #pragma unroll
            for (int c = 0; c < 4; ++c) {
                const int linear = fidx * 4 + c;      // = k*64 + col
                const int k   = linear >> 6;
                const int col = linear & 63;
                const int ks   = k >> 5;
                const int kw   = k & 31;
                const int quad = kw >> 3;
                const int jj   = (kw & 7) >> 1;
                const int b    = kw & 1;
                const int nt   = col >> 4;
                const int r    = col & 15;
                const int dst = ((((ks * 4 + nt) * 4 + quad) * 16 + r) * 8) + jj * 2 + b;
                const float fv = (c == 0) ? v.x : (c == 1) ? v.y : (c == 2) ? v.z : v.w;
                B2U cv; cv.b = __float2bfloat16(fv);
                sW16[dst] = cv.u;
            }
        }
    }
    __syncthreads();

    const int lane = threadIdx.x & 63;
    const int r    = lane & 15;
    const int quad = lane >> 4;

    short8 Wb[4][4];   // [kstep][ntile]: one ds_read_b128 each
    #pragma unroll
    for (int ks = 0; ks < 4; ++ks)
        #pragma unroll
        for (int nt = 0; nt < 4; ++nt)
            Wb[ks][nt] = *(const short8*)&sW16[(((ks * 4 + nt) * 4 + quad) * 16 + r) * 8];

    float bias[4];
    #pragma unroll
    for (int nt = 0; nt < 4; ++nt) bias[nt] = be[nt * 16 + r];

    const int wid    = (blockIdx.x * 256 + threadIdx.x) >> 6;
    const int nwaves = gridDim.x * 4;

    const int estride = gridDim.x * 256;
    int e = blockIdx.x * 256 + threadIdx.x;

    for (int t = wid; t < n_tiles; t += nwaves) {
        const float* Arow = A + (size_t)t * 16 * NODE_DIM + (size_t)r * NODE_DIM + quad * 8;
        float4 a[4][2];
        #pragma unroll
        for (int ks = 0; ks < 4; ++ks) {
            a[ks][0] = *(const float4*)(Arow + ks * 32);
            a[ks][1] = *(const float4*)(Arow + ks * 32 + 4);
        }

        // --- interleaved edge chunk: 3 edges per thread per tile iter ---
        #pragma unroll
        for (int q = 0; q < 3; ++q) {
            if (e < n_edges) {
                const int d = dsts[e];
                if ((bits[d >> 5] >> (d & 31)) & 1u)
                    rank[e] = atomicAdd(&count[d], 1);
                e += estride;
            }
        }

        floatx4 acc[4] = {};
        #pragma unroll
        for (int ks = 0; ks < 4; ++ks) {
            const short8 af = cvt8(a[ks][0], a[ks][1]);
            #pragma unroll
            for (int nt = 0; nt < 4; ++nt)
                acc[nt] = __builtin_amdgcn_mfma_f32_16x16x32_bf16(af, Wb[ks][nt], acc[nt], 0, 0, 0);
        }
        #pragma unroll
        for (int nt = 0; nt < 4; ++nt)
            #pragma unroll
            for (int g = 0; g < 4; ++g) {
                const int node = t * 16 + quad * 4 + g;
                const float h = fmaxf(acc[nt][g] + bias[nt], 0.0f);
                emb16[(size_t)node * HIDDEN + nt * 16 + r] = __float2bfloat16(h);
            }
    }
    // tail nodes (n_nodes % 16) — 0 for this shape
    const int rem = n_nodes - n_tiles * 16;
    if (rem > 0 && wid == 0) {
        for (int n = n_tiles * 16; n < n_nodes; ++n) {
            float acc = be[lane];
            const float* row = A + (size_t)n * NODE_DIM;
            for (int k = 0; k < NODE_DIM; ++k)
                acc = fmaf(row[k], We[(size_t)k * HIDDEN + lane], acc);
            emb16[(size_t)n * HIDDEN + lane] = __float2bfloat16(fmaxf(acc, 0.0f));
        }
    }

    // --- drain remaining edges ---
    for (; e < n_edges; e += estride) {
        const int d = dsts[e];
        if ((bits[d >> 5] >> (d & 31)) & 1u)
            rank[e] = atomicAdd(&count[d], 1);
    }
}

// ---------------------------------------------------------------------------
// CSR step 2: single-pass exclusive scan, decoupled lookback with a
// WAVE-PARALLEL window (64 partials per round, ballot on states).
// ---------------------------------------------------------------------------
__global__ __launch_bounds__(256) void k_scan_lb(
    const int* __restrict__ count, int* __restrict__ row_start,
    unsigned int* __restrict__ partials, int n)
{
    __shared__ int s[256];
    __shared__ int sExc;
    const int b = blockIdx.x, tid = threadIdx.x;
    const int base = b * SCAN_CHUNK + tid * 4;
    int c0 = (base + 0 < n) ? count[base + 0] : 0;
    int c1 = (base + 1 < n) ? count[base + 1] : 0;
    int c2 = (base + 2 < n) ? count[base + 2] : 0;
    int c3 = (base + 3 < n) ? count[base + 3] : 0;
    const int t = c0 + c1 + c2 + c3;
    s[tid] = t;
    __syncthreads();
    #pragma unroll
    for (int off = 1; off < 256; off <<= 1) {
        int v = (tid >= off) ? s[tid - off] : 0;
        __syncthreads();
        s[tid] += v;
        __syncthreads();
    }
    const int total = s[255];

    if (b == 0) {
        if (tid == 0) {
            __hip_atomic_store(&partials[0], (2u << 30) | (unsigned int)total,
                               __ATOMIC_RELEASE, __HIP_MEMORY_SCOPE_AGENT);
            sExc = 0;
        }
    } else {
        if (tid == 0) {
            __hip_atomic_store(&partials[b], (1u << 30) | (unsigned int)total,
                               __ATOMIC_RELEASE, __HIP_MEMORY_SCOPE_AGENT);
        }
        if (tid < 64) {
            int exc = 0;
            int winEnd = b;            // scan window [winEnd-64, winEnd)
            while (true) {
                const int j = winEnd - 64 + tid;
                const unsigned int v = (j >= 0)
                    ? __hip_atomic_load(&partials[j], __ATOMIC_ACQUIRE,
                                        __HIP_MEMORY_SCOPE_AGENT)
                    : (2u << 30);      // synthetic prefix: guarantees ballot2
                const unsigned int st = v >> 30;
                if (__ballot(st == 0u)) {           // someone not posted yet
                    __builtin_amdgcn_s_sleep(1);
                    continue;
                }
                const unsigned long long b2 = __ballot(st == 2u);
                int contrib;
                bool done;
                if (b2) {
                    const int hi = 63 - __clzll(b2); // nearest prefix to us
                    contrib = (tid >= hi) ? (int)(v & 0x3FFFFFFFu) : 0;
                    done = true;
                } else {
                    contrib = (int)(v & 0x3FFFFFFFu); // all aggregates
                    done = false;
                }
                #pragma unroll
                for (int off = 1; off < 64; off <<= 1)
                    contrib += __shfl_xor(contrib, off);
                exc += contrib;
                if (done) break;
                winEnd -= 64;
            }
            if (tid == 0) {
                __hip_atomic_store(&partials[b],
                                   (2u << 30) | (unsigned int)(exc + total),
                                   __ATOMIC_RELEASE, __HIP_MEMORY_SCOPE_AGENT);
                sExc = exc;
            }
        }
    }
    __syncthreads();
    int run = sExc + s[tid] - t;
    if (base + 0 < n) row_start[base + 0] = run;           run += c0;
    if (base + 1 < n) row_start[base + 1] = run;           run += c1;
    if (base + 2 < n) row_start[base + 2] = run;           run += c2;
    if (base + 3 < n) row_start[base + 3] = run;
}

// CSR step 3: fill slot lists — ATOMIC-FREE via precomputed rank.
__global__ __launch_bounds__(256) void k_fill(
    const int* __restrict__ srcs, const int* __restrict__ dsts,
    const unsigned int* __restrict__ bits, const int* __restrict__ row_start,
    const int* __restrict__ rank, int* __restrict__ slots, int n_edges)
{
    const int stride = gridDim.x * 256;
    for (int e = blockIdx.x * 256 + threadIdx.x; e < n_edges; e += stride) {
        const int d = dsts[e];
        if (!((bits[d >> 5] >> (d & 31)) & 1u)) continue;
        slots[row_start[d] + rank[e]] = srcs[e];
    }
}

// ---------------------------------------------------------------------------
// FUSED gather+head: wave per 16-compact-node tile. Lane (r,quad) gathers
// node nodelist[i0+r]'s channel octets quad (ks=0) and 4+quad (ks=1) as f32
// sums — exactly the head A-fragment — then the wave runs the head MFMA and
// writes res[node]. msg_c never exists.
// ---------------------------------------------------------------------------
__global__ __launch_bounds__(256) void k_gather_head(
    const int* __restrict__ nodelist, const int* __restrict__ listCnt,
    const int* __restrict__ row_start, const int* __restrict__ count,
    const int* __restrict__ slots, const __hip_bfloat16* __restrict__ emb16,
    const float* __restrict__ Wc, const float* __restrict__ bc,
    const float* __restrict__ Wo, const float* __restrict__ bo,
    float* __restrict__ res)
{
    const int lane = threadIdx.x & 63;
    const int r    = lane & 15;
    const int quad = lane >> 4;

    // head weight fragments (per wave, from L2-resident 16KB Wc)
    short8 Wb[2][4];
    #pragma unroll
    for (int ks = 0; ks < 2; ++ks)
        #pragma unroll
        for (int nt = 0; nt < 4; ++nt) {
            F2B u;
            #pragma unroll
            for (int jj = 0; jj < 4; ++jj) {
                const int k0 = ks * 32 + quad * 8 + 2 * jj;
                const float lo = Wc[(size_t)k0 * HIDDEN + nt * 16 + r];
                const float hi = Wc[(size_t)(k0 + 1) * HIDDEN + nt * 16 + r];
                u.h[jj] = __float22bfloat162_rn(make_float2(lo, hi));
            }
            Wb[ks][nt] = u.s;
        }
    float bias[4], wo[4];
    #pragma unroll
    for (int nt = 0; nt < 4; ++nt) { bias[nt] = bc[nt * 16 + r]; wo[nt] = Wo[nt * 16 + r]; }
    const float bo_s = bo[0];

    const int nc      = listCnt[0];
    const int n_tiles = (nc + 15) / 16;
    const int wid     = (blockIdx.x * 256 + threadIdx.x) >> 6;
    const int nwaves  = gridDim.x * 4;

    for (int tile = wid; tile < n_tiles; tile += nwaves) {
        const int i0  = tile * 16;
        const int row = i0 + r;

        // ---- gather phase: f32 sums for octet quad (ch quad*8..+7) and
        //      octet 4+quad (ch 32+quad*8..+7) of node nodelist[row] ----
        float4 f0a = make_float4(0.f, 0.f, 0.f, 0.f), f0b = f0a;  // ks=0 octet
        float4 f1a = f0a, f1b = f0a;                              // ks=1 octet
        if (row < nc) {
            const int n    = nodelist[row];
            const int m    = count[n];
            const int base = row_start[n];
            const size_t o0 = (size_t)n * HIDDEN + quad * 8;

            #define ACC2(vlo, vhi) do {                                          \
                F2B ua, ub; ua.s = (vlo); ub.s = (vhi); float2 t2;               \
                t2 = __bfloat1622float2(ua.h[0]); f0a.x += t2.x; f0a.y += t2.y;  \
                t2 = __bfloat1622float2(ua.h[1]); f0a.z += t2.x; f0a.w += t2.y;  \
                t2 = __bfloat1622float2(ua.h[2]); f0b.x += t2.x; f0b.y += t2.y;  \
                t2 = __bfloat1622float2(ua.h[3]); f0b.z += t2.x; f0b.w += t2.y;  \
                t2 = __bfloat1622float2(ub.h[0]); f1a.x += t2.x; f1a.y += t2.y;  \
                t2 = __bfloat1622float2(ub.h[1]); f1a.z += t2.x; f1a.w += t2.y;  \
                t2 = __bfloat1622float2(ub.h[2]); f1b.x += t2.x; f1b.y += t2.y;  \
                t2 = __bfloat1622float2(ub.h[3]); f1b.z += t2.x; f1b.w += t2.y;  \
            } while (0)

            {   // self row
                const short8 vlo = *(const short8*)(emb16 + o0);
                const short8 vhi = *(const short8*)(emb16 + o0 + 32);
                ACC2(vlo, vhi);
            }
            int c = 0;
            for (; c + 1 < m; c += 2) {
                const int s0 = slots[base + c];
                const int s1 = slots[base + c + 1];
                const size_t a0 = (size_t)s0 * HIDDEN + quad * 8;
                const size_t a1 = (size_t)s1 * HIDDEN + quad * 8;
                const short8 v0lo = *(const short8*)(emb16 + a0);
                const short8 v0hi = *(const short8*)(emb16 + a0 + 32);
                const short8 v1lo = *(const short8*)(emb16 + a1);
                const short8 v1hi = *(const short8*)(emb16 + a1 + 32);
                ACC2(v0lo, v0hi);
                ACC2(v1lo, v1hi);
            }
            if (c < m) {
                const int s0 = slots[base + c];
                const size_t a0 = (size_t)s0 * HIDDEN + quad * 8;
                const short8 v0lo = *(const short8*)(emb16 + a0);
                const short8 v0hi = *(const short8*)(emb16 + a0 + 32);
                ACC2(v0lo, v0hi);
            }
            #undef ACC2
        }

        // ---- head phase: identical math to k_head_mfma ----
        floatx4 acc[4] = {};
        {
            short8 ah, al;
            cvt8_split(f0a, f0b, ah, al);
            #pragma unroll
            for (int nt = 0; nt < 4; ++nt) {
                acc[nt] = __builtin_amdgcn_mfma_f32_16x16x32_bf16(ah, Wb[0][nt], acc[nt], 0, 0, 0);
                acc[nt] = __builtin_amdgcn_mfma_f32_16x16x32_bf16(al, Wb[0][nt], acc[nt], 0, 0, 0);
            }
            cvt8_split(f1a, f1b, ah, al);
            #pragma unroll
            for (int nt = 0; nt < 4; ++nt) {
                acc[nt] = __builtin_amdgcn_mfma_f32_16x16x32_bf16(ah, Wb[1][nt], acc[nt], 0, 0, 0);
                acc[nt] = __builtin_amdgcn_mfma_f32_16x16x32_bf16(al, Wb[1][nt], acc[nt], 0, 0, 0);
            }
        }
        float r4[4];
        #pragma unroll
        for (int gg = 0; gg < 4; ++gg) {
            float part = 0.0f;
            #pragma unroll
            for (int nt = 0; nt < 4; ++nt)
                part += fmaxf(acc[nt][gg] + bias[nt], 0.0f) * wo[nt];
            part += __shfl_xor(part, 1);
            part += __shfl_xor(part, 2);
            part += __shfl_xor(part, 4);
            part += __shfl_xor(part, 8);
            r4[gg] = part;
        }
        if (r == 0) {
            #pragma unroll
            for (int gg = 0; gg < 4; ++gg) {
                const int idx = i0 + quad * 4 + gg;
                if (idx < nc)
                    res[nodelist[idx]] = 1.0f / (1.0f + __expf(-(r4[gg] + bo_s)));
            }
        }
    }
}

// Final map: out[p] = res[post[p]] (single random L2 read).
__global__ __launch_bounds__(256) void k_out(
    const int* __restrict__ post, const float* __restrict__ res,
    float* __restrict__ out, int n_posts)
{
    const int p = blockIdx.x * 256 + threadIdx.x;
    if (p < n_posts) out[p] = res[post[p]];
}

extern "C" void kernel_launch(void* const* d_in, const int* in_sizes, int n_in,
                              void* d_out, int out_size, void* d_ws, size_t ws_size,
                              hipStream_t stream) {
    const float* A    = (const float*)d_in[0];
    const int*   ei   = (const int*)  d_in[1];
    const int*   post = (const int*)  d_in[2];
    const float* We   = (const float*)d_in[3];
    const float* be   = (const float*)d_in[4];
    const float* Wc   = (const float*)d_in[5];
    const float* bc   = (const float*)d_in[6];
    const float* Wo   = (const float*)d_in[7];
    const float* bo   = (const float*)d_in[8];
    float* out = (float*)d_out;

    const int n_nodes = in_sizes[0] / NODE_DIM;   // 100000
    const int n_edges = in_sizes[1] / 2;          // 1200000
    const int n_posts = in_sizes[2];              // 50000

    // ---- workspace layout (~25 MB; every region written before read) ----
    char* p = (char*)d_ws;
    __hip_bfloat16* emb16 = (__hip_bfloat16*)p;  p += (size_t)n_nodes * HIDDEN * 2;  // 12.8 MB
    int*   slots    = (int*)p;                p += (size_t)n_edges * 4;              // 4.8 MB
    int*   rank     = (int*)p;                p += (size_t)n_edges * 4;              // 4.8 MB
    // small ctrl region zeroed by memset: bits | listCnt | partials
    char* zbase = p;
    unsigned int* bits = (unsigned int*)p;    p += ((size_t)(n_nodes + 31) / 32 + 32) * 4;
    int*   listCnt  = (int*)p;                p += 256;
    unsigned int* partials = (unsigned int*)p; p += 1024;
    const size_t zbytes = (size_t)(p - zbase);                                       // ~14 KB
    int*   count    = (int*)p;                p += (size_t)n_nodes * 4;   // zeroed in k_pre
    int*   row_start= (int*)p;                p += (size_t)n_nodes * 4;
    int*   nodelist = (int*)p;                p += (size_t)n_nodes * 4;
    float* res      = (float*)p;              p += (size_t)n_nodes * 4;

    const int* srcs = ei;
    const int* dsts = ei + n_edges;
    const int nb = (n_nodes + SCAN_CHUNK - 1) / SCAN_CHUNK;   // 98
    const int n_tiles = n_nodes / 16;

    (void)hipMemsetAsync(zbase, 0, zbytes, stream);
    k_pre<<<(n_nodes + 255) / 256, 256, 0, stream>>>(post, bits, nodelist, listCnt, count, n_posts, n_nodes);
    k_encode_count<<<1536, 256, 0, stream>>>(A, We, be, emb16, dsts, bits, count, rank, n_nodes, n_tiles, n_edges);
    k_scan_lb<<<nb, 256, 0, stream>>>(count, row_start, partials, n_nodes);
    k_fill<<<2048, 256, 0, stream>>>(srcs, dsts, bits, row_start, rank, slots, n_edges);
    k_gather_head<<<1024, 256, 0, stream>>>(nodelist, listCnt, row_start, count, slots, emb16, Wc, bc, Wo, bo, res);
    k_out<<<(n_posts + 255) / 256, 256, 0, stream>>>(post, res, out, n_posts);
}